// Round 1
// baseline (2997.044 us; speedup 1.0000x reference)
//
#include <hip/hip_runtime.h>
#include <hip/hip_bf16.h>

// Problem constants
#define BB   32
#define NT   320      // T rows per batch
#define LX   704
#define TMPL 128
#define NS   576      // LX - TMPL
#define CC   768
#define LN_EPS 1e-5f

// ---------------- block reduction helpers (blockDim == 256) ----------------
__device__ __forceinline__ float block_sum256(float v) {
    __shared__ float sm[4];
    #pragma unroll
    for (int o = 32; o > 0; o >>= 1) v += __shfl_down(v, o, 64);
    __syncthreads();
    if ((threadIdx.x & 63) == 0) sm[threadIdx.x >> 6] = v;
    __syncthreads();
    return sm[0] + sm[1] + sm[2] + sm[3];
}

__device__ __forceinline__ float block_max256(float v) {
    __shared__ float sm[4];
    #pragma unroll
    for (int o = 32; o > 0; o >>= 1) v = fmaxf(v, __shfl_down(v, o, 64));
    __syncthreads();
    if ((threadIdx.x & 63) == 0) sm[threadIdx.x >> 6] = v;
    __syncthreads();
    return fmaxf(fmaxf(sm[0], sm[1]), fmaxf(sm[2], sm[3]));
}

// ---------------- generic 64x64 tiled fp32 GEMM ----------------
// C[b] = alpha * A[b] @ B[b] (+ C if ACC). A row-major MxK (K contiguous).
// BT=false: B is KxN row-major (N contiguous).  BT=true: B is NxK row-major
// (dot of rows, i.e. C = A @ B^T).
// Requires M % 64 == 0, N % 64 == 0, K % 16 == 0. blockDim = 256.
template<bool BT, bool ACC>
__global__ void gemm_tile(const float* __restrict__ A, const float* __restrict__ Bm,
                          float* __restrict__ Cm,
                          int M, int N, int K,
                          long sA, long oA, long sB, long sC, float alpha)
{
    // 66 stride: conflict-free LDS writes for k-major fills (2k mod 32 distinct)
    __shared__ float As[16][66];
    __shared__ float Bs[16][66];
    const int b = blockIdx.z;
    const float* Ab = A + (long)b * sA + oA;
    const float* Bb = Bm + (long)b * sB;
    float* Cb = Cm + (long)b * sC;
    const int n0 = blockIdx.x * 64;
    const int m0 = blockIdx.y * 64;
    const int tid = threadIdx.x;
    const int tx = tid & 15;
    const int ty = tid >> 4;

    float acc[4][4] = {};

    for (int k0 = 0; k0 < K; k0 += 16) {
        #pragma unroll
        for (int l = 0; l < 4; ++l) {
            int idx = tid + 256 * l;
            int kk = idx & 15, mm = idx >> 4;
            As[kk][mm] = Ab[(long)(m0 + mm) * K + k0 + kk];
        }
        if (BT) {
            #pragma unroll
            for (int l = 0; l < 4; ++l) {
                int idx = tid + 256 * l;
                int kk = idx & 15, nn = idx >> 4;
                Bs[kk][nn] = Bb[(long)(n0 + nn) * K + k0 + kk];
            }
        } else {
            #pragma unroll
            for (int l = 0; l < 4; ++l) {
                int idx = tid + 256 * l;
                int nn = idx & 63, kk = idx >> 6;
                Bs[kk][nn] = Bb[(long)(k0 + kk) * N + n0 + nn];
            }
        }
        __syncthreads();
        #pragma unroll
        for (int kk = 0; kk < 16; ++kk) {
            float a[4], bv[4];
            #pragma unroll
            for (int i = 0; i < 4; ++i) a[i] = As[kk][ty + 16 * i];
            #pragma unroll
            for (int j = 0; j < 4; ++j) bv[j] = Bs[kk][tx + 16 * j];
            #pragma unroll
            for (int i = 0; i < 4; ++i)
                #pragma unroll
                for (int j = 0; j < 4; ++j)
                    acc[i][j] += a[i] * bv[j];
        }
        __syncthreads();
    }

    #pragma unroll
    for (int i = 0; i < 4; ++i)
        #pragma unroll
        for (int j = 0; j < 4; ++j) {
            long off = (long)(m0 + ty + 16 * i) * N + (n0 + tx + 16 * j);
            float vout = acc[i][j] * alpha;
            if (ACC) Cb[off] += vout; else Cb[off] = vout;
        }
}

// ---------------- row softmax over 576 columns, in place ----------------
// grid = num_rows, block = 256
__global__ void softmax_rows576(float* __restrict__ P)
{
    float* p = P + (long)blockIdx.x * NS;
    const int tid = threadIdx.x;
    float v0 = p[tid];
    float v1 = p[tid + 256];
    float v2 = (tid < NS - 512) ? p[tid + 512] : -1e30f;
    float m = block_max256(fmaxf(fmaxf(v0, v1), v2));
    float e0 = __expf(v0 - m);
    float e1 = __expf(v1 - m);
    float e2 = (tid < NS - 512) ? __expf(v2 - m) : 0.f;
    float s = block_sum256(e0 + e1 + e2);
    float inv = 1.f / s;
    p[tid]       = e0 * inv;
    p[tid + 256] = e1 * inv;
    if (tid < NS - 512) p[tid + 512] = e2 * inv;
}

// ---------------- D = aw - awi sign counts per (b, n) column ----------------
// grid = BB*NS/256, block = 256. ratios[2g] = rgb+eq (coef for v),
// ratios[2g+1] = tir+eq (coef for vi)
__global__ void count_ratio(const float* __restrict__ aw, const float* __restrict__ awi,
                            float* __restrict__ ratios)
{
    int g = blockIdx.x * 256 + threadIdx.x;     // 0 .. BB*NS-1
    int b = g / NS, n = g - b * NS;
    const float* pa = aw  + (long)b * NT * NS + n;
    const float* pb = awi + (long)b * NT * NS + n;
    int ones = 0, eq = 0;
    #pragma unroll 8
    for (int t = 0; t < NT; ++t) {
        float d = pa[(long)t * NS] - pb[(long)t * NS];
        ones += (d > 0.f);
        eq   += (d == 0.f);
    }
    float rgb = (float)ones * (1.f / NT);
    float e   = (float)eq   * (1.f / NT);
    ratios[2 * g]     = rgb + e;
    ratios[2 * g + 1] = (1.f - rgb - e) + e;
}

// ---------------- x_s = v*coef_v + vi*coef_vi ----------------
__global__ void xs_kernel(const float* __restrict__ v, const float* __restrict__ vi,
                          const float* __restrict__ ratios, float* __restrict__ out)
{
    long i = (long)blockIdx.x * 256 + threadIdx.x;   // over BB*NS*CC
    long row = i / CC;
    out[i] = v[i] * ratios[2 * row] + vi[i] * ratios[2 * row + 1];
}

// ---------------- T_new = LayerNorm(T + S2) ----------------
// grid = BB*NT rows, block = 256 (3 elements/thread over C=768)
__global__ void add_ln(const float* __restrict__ T, const float* __restrict__ S2,
                       const float* __restrict__ gamma, const float* __restrict__ beta,
                       float* __restrict__ out)
{
    long row = blockIdx.x;
    const int tid = threadIdx.x;
    const float* t = T  + row * CC;
    const float* s = S2 + row * CC;
    float h[3];
    float sum = 0.f;
    #pragma unroll
    for (int i = 0; i < 3; ++i) {
        h[i] = t[tid + 256 * i] + s[tid + 256 * i];
        sum += h[i];
    }
    sum = block_sum256(sum);
    float mu = sum * (1.f / CC);
    float varp = 0.f;
    #pragma unroll
    for (int i = 0; i < 3; ++i) { float d = h[i] - mu; varp += d * d; }
    varp = block_sum256(varp);
    float inv = rsqrtf(varp * (1.f / CC) + LN_EPS);
    #pragma unroll
    for (int i = 0; i < 3; ++i) {
        int c = tid + 256 * i;
        out[row * CC + c] = (h[i] - mu) * inv * gamma[c] + beta[c];
    }
}

// ---------------- launch ----------------
extern "C" void kernel_launch(void* const* d_in, const int* in_sizes, int n_in,
                              void* d_out, int out_size, void* d_ws, size_t ws_size,
                              hipStream_t stream) {
    const float* T     = (const float*)d_in[0];
    const float* x     = (const float*)d_in[1];
    const float* xi    = (const float*)d_in[2];
    const float* Wq    = (const float*)d_in[3];
    const float* Wk    = (const float*)d_in[4];
    const float* Wv    = (const float*)d_in[5];
    const float* Wout  = (const float*)d_in[6];
    const float* gamma = (const float*)d_in[7];
    const float* beta  = (const float*)d_in[8];
    float* out = (float*)d_out;

    // workspace layout (floats)
    const long SZ_Q  = (long)BB * NT * CC;   //  7,864,320
    const long SZ_KV = (long)BB * NS * CC;   // 14,155,776
    const long SZ_AW = (long)BB * NT * NS;   //  5,898,240
    const long SZ_RT = 2L * BB * NS;

    float* q   = (float*)d_ws;          // later reused as S2
    float* k   = q   + SZ_Q;            // later reused as S
    float* ki  = k   + SZ_KV;
    float* v   = ki  + SZ_KV;
    float* vi  = v   + SZ_KV;
    float* aw  = vi  + SZ_KV;
    float* awi = aw  + SZ_AW;
    float* ratios = awi + SZ_AW;
    size_t need = (size_t)(SZ_Q + 4 * SZ_KV + 2 * SZ_AW + SZ_RT) * sizeof(float);
    if (ws_size < need) return;  // workspace too small: bail cleanly (will restructure)

    float* S  = k;   // k dead after logits
    float* S2 = q;   // q dead after logits

    const float scale = 1.0f / sqrtf((float)CC);
    dim3 blk(256);

    // 1. projections (batched over z=32)
    // q = T @ Wq                (M=320)
    gemm_tile<false, false><<<dim3(CC / 64, NT / 64, BB), blk, 0, stream>>>(
        T, Wq, q, NT, CC, CC, (long)NT * CC, 0, 0, (long)NT * CC, 1.f);
    // k = xs @ Wk, ki = xis @ Wk, v = xs @ Wv, vi = xis @ Wv   (M=576, skip TMPL rows)
    gemm_tile<false, false><<<dim3(CC / 64, NS / 64, BB), blk, 0, stream>>>(
        x,  Wk, k,  NS, CC, CC, (long)LX * CC, (long)TMPL * CC, 0, (long)NS * CC, 1.f);
    gemm_tile<false, false><<<dim3(CC / 64, NS / 64, BB), blk, 0, stream>>>(
        xi, Wk, ki, NS, CC, CC, (long)LX * CC, (long)TMPL * CC, 0, (long)NS * CC, 1.f);
    gemm_tile<false, false><<<dim3(CC / 64, NS / 64, BB), blk, 0, stream>>>(
        x,  Wv, v,  NS, CC, CC, (long)LX * CC, (long)TMPL * CC, 0, (long)NS * CC, 1.f);
    gemm_tile<false, false><<<dim3(CC / 64, NS / 64, BB), blk, 0, stream>>>(
        xi, Wv, vi, NS, CC, CC, (long)LX * CC, (long)TMPL * CC, 0, (long)NS * CC, 1.f);

    // 2. logits: aw = scale * q @ k^T, awi = scale * q @ ki^T
    gemm_tile<true, false><<<dim3(NS / 64, NT / 64, BB), blk, 0, stream>>>(
        q, k,  aw,  NT, NS, CC, (long)NT * CC, 0, (long)NS * CC, (long)NT * NS, scale);
    gemm_tile<true, false><<<dim3(NS / 64, NT / 64, BB), blk, 0, stream>>>(
        q, ki, awi, NT, NS, CC, (long)NT * CC, 0, (long)NS * CC, (long)NT * NS, scale);

    // 3. softmax in place
    softmax_rows576<<<BB * NT, blk, 0, stream>>>(aw);
    softmax_rows576<<<BB * NT, blk, 0, stream>>>(awi);

    // 4. ratios from sign counts of D = aw - awi
    count_ratio<<<(BB * NS) / 256, blk, 0, stream>>>(aw, awi, ratios);

    // 5. x_s -> d_out[0 : BB*NS*CC]
    xs_kernel<<<(BB * NS * CC) / 256, blk, 0, stream>>>(v, vi, ratios, out);

    // 6. S = aw @ v + awi @ vi   (into dead k buffer)
    gemm_tile<false, false><<<dim3(CC / 64, NT / 64, BB), blk, 0, stream>>>(
        aw,  v,  S, NT, CC, NS, (long)NT * NS, 0, (long)NS * CC, (long)NT * CC, 1.f);
    gemm_tile<false, true><<<dim3(CC / 64, NT / 64, BB), blk, 0, stream>>>(
        awi, vi, S, NT, CC, NS, (long)NT * NS, 0, (long)NS * CC, (long)NT * CC, 1.f);

    // 7. S2 = S @ Wout   (into dead q buffer)
    gemm_tile<false, false><<<dim3(CC / 64, NT / 64, BB), blk, 0, stream>>>(
        S, Wout, S2, NT, CC, CC, (long)NT * CC, 0, 0, (long)NT * CC, 1.f);

    // 8. T_new = LN(T + S2) -> d_out[BB*NS*CC : ]
    add_ln<<<BB * NT, blk, 0, stream>>>(T, S2, gamma, beta, out + (long)BB * NS * CC);
}

// Round 2
// 724.956 us; speedup vs baseline: 4.1341x; 4.1341x over previous
//
#include <hip/hip_runtime.h>

// Problem constants
#define BB   32
#define NT   320      // T rows per batch
#define NTP  384      // NT padded to 128 multiple
#define LX   704
#define TMPL 128
#define NS   576      // LX - TMPL
#define NSP  640      // NS padded to 128 multiple
#define CC   768
#define NS2  1152     // 2*NS (k|ki concat, v|vi concat)
#define LN_EPS 1e-5f

typedef __attribute__((ext_vector_type(8))) short short8;   // 8 bf16 (4 VGPRs)
typedef __attribute__((ext_vector_type(4))) float f32x4;

typedef __attribute__((address_space(3))) void as3_void;
typedef __attribute__((address_space(1))) void as1_void;
#define GLDS16(g, l) __builtin_amdgcn_global_load_lds((const as1_void*)(g), (as3_void*)(l), 16, 0, 0)

__device__ __forceinline__ unsigned short f2bf(float f) {
    union { float f; unsigned u; } v; v.f = f;
    unsigned r = v.u + 0x7FFFu + ((v.u >> 16) & 1u);   // round-to-nearest-even
    return (unsigned short)(r >> 16);
}
__device__ __forceinline__ float bf2f(unsigned short h) {
    union { unsigned u; float f; } v; v.u = ((unsigned)h) << 16;
    return v.f;
}

// ---------------- block reduction helpers (blockDim == 256) ----------------
__device__ __forceinline__ float block_sum256(float v) {
    __shared__ float sm[4];
    #pragma unroll
    for (int o = 32; o > 0; o >>= 1) v += __shfl_down(v, o, 64);
    __syncthreads();
    if ((threadIdx.x & 63) == 0) sm[threadIdx.x >> 6] = v;
    __syncthreads();
    return sm[0] + sm[1] + sm[2] + sm[3];
}
__device__ __forceinline__ float block_max256(float v) {
    __shared__ float sm[4];
    #pragma unroll
    for (int o = 32; o > 0; o >>= 1) v = fmaxf(v, __shfl_down(v, o, 64));
    __syncthreads();
    if ((threadIdx.x & 63) == 0) sm[threadIdx.x >> 6] = v;
    __syncthreads();
    return fmaxf(fmaxf(sm[0], sm[1]), fmaxf(sm[2], sm[3]));
}

// =================== bf16 MFMA GEMM (m97 structure) ===================
// C[b](M x N) = alpha * A[b](M x K, row-major bf16) @ Bt[b](N x K, row-major bf16)^T
// 128x128 tile, BK=32, 256 threads = 4 waves in 2x2, each wave 64x64 (4x4 MFMA 16x16x32).
// A must be readable up to gridDim.y*128 rows (padded buffers); stores guarded by M.
// N % 128 == 0, K % 32 == 0.
template<bool F32OUT>
__global__ __launch_bounds__(256) void gemm_bt(
    const short* __restrict__ A, const short* __restrict__ Bt, void* __restrict__ Cv,
    int M, int N, int K, long sA, long sB, long sC, float alpha)
{
    __shared__ short As[128 * 32];
    __shared__ short Bs[128 * 32];
    const int b  = blockIdx.z;
    const short* Ab = A  + (long)b * sA;
    const short* Bb = Bt + (long)b * sB;
    const int m0 = blockIdx.y * 128;
    const int n0 = blockIdx.x * 128;
    const int tid  = threadIdx.x;
    const int lane = tid & 63;
    const int w    = tid >> 6;
    const int wr   = (w >> 1) * 64;   // wave row in tile
    const int wc   = (w & 1) * 64;    // wave col in tile

    // staging: thread t loads 16B from row (t>>2), k-offset (t&3)*8 -> LDS offset t*8 shorts
    const int srow = tid >> 2;
    const int scol = (tid & 3) * 8;
    const short* gA0 = Ab + (long)(m0 + srow) * K + scol;
    const short* gA1 = gA0 + (long)64 * K;
    const short* gB0 = Bb + (long)(n0 + srow) * K + scol;
    const short* gB1 = gB0 + (long)64 * K;
    short* lA0 = As + srow * 32 + scol;     // == As + tid*8  (lane-contiguous)
    short* lA1 = lA0 + 64 * 32;
    short* lB0 = Bs + srow * 32 + scol;
    short* lB1 = lB0 + 64 * 32;

    const int fl = lane & 15;         // m/n within 16-tile
    const int fk = (lane >> 4) * 8;   // k block

    f32x4 acc[4][4] = {};

    for (int k0 = 0; k0 < K; k0 += 32) {
        GLDS16(gA0 + k0, lA0);
        GLDS16(gA1 + k0, lA1);
        GLDS16(gB0 + k0, lB0);
        GLDS16(gB1 + k0, lB1);
        __syncthreads();   // compiler emits vmcnt(0) drain before barrier

        short8 af[4], bfr[4];
        #pragma unroll
        for (int mt = 0; mt < 4; ++mt)
            af[mt] = *(const short8*)(As + (wr + mt * 16 + fl) * 32 + fk);
        #pragma unroll
        for (int nt = 0; nt < 4; ++nt)
            bfr[nt] = *(const short8*)(Bs + (wc + nt * 16 + fl) * 32 + fk);
        #pragma unroll
        for (int mt = 0; mt < 4; ++mt)
            #pragma unroll
            for (int nt = 0; nt < 4; ++nt)
                acc[mt][nt] = __builtin_amdgcn_mfma_f32_16x16x32_bf16(
                    af[mt], bfr[nt], acc[mt][nt], 0, 0, 0);
        __syncthreads();
    }

    // epilogue: C/D layout col=lane&15, row=(lane>>4)*4+reg
    float* Cf = (float*)Cv;
    unsigned short* Ch = (unsigned short*)Cv;
    const int rq = (lane >> 4) * 4;
    const long cb = (long)b * sC;
    #pragma unroll
    for (int mt = 0; mt < 4; ++mt) {
        #pragma unroll
        for (int r = 0; r < 4; ++r) {
            int row = m0 + wr + mt * 16 + rq + r;
            if (row >= M) continue;
            long ro = cb + (long)row * N + n0 + wc + fl;
            #pragma unroll
            for (int nt = 0; nt < 4; ++nt) {
                float val = acc[mt][nt][r] * alpha;
                if (F32OUT) Cf[ro + nt * 16] = val;
                else        Ch[ro + nt * 16] = f2bf(val);
            }
        }
    }
}

// =================== converters ===================
// fp32 [B][srcRows][CC] (row offset srcOff) -> bf16 [B][Mpad][CC], pad rows zeroed.
__global__ void conv_pad(const float* __restrict__ src, unsigned short* __restrict__ dst,
                         int Mreal, int Mpad, int srcRows, int srcOff)
{
    long i4 = ((long)blockIdx.x * 256 + threadIdx.x) * 4;   // over B*Mpad*CC
    int c   = (int)(i4 % CC);
    long rw = i4 / CC;
    int t   = (int)(rw % Mpad);
    int b   = (int)(rw / Mpad);
    ushort4 o;
    if (t < Mreal) {
        const float4 f = *(const float4*)(src + ((long)b * srcRows + srcOff + t) * CC + c);
        o.x = f2bf(f.x); o.y = f2bf(f.y); o.z = f2bf(f.z); o.w = f2bf(f.w);
    } else {
        o.x = o.y = o.z = o.w = 0;
    }
    *(ushort4*)(dst + i4) = o;
}

// fp32 W [CC][CC] -> bf16 W^T [CC][CC]
__global__ void conv_wt(const float* __restrict__ W, unsigned short* __restrict__ WT)
{
    __shared__ float tile[32][33];
    const int c0 = blockIdx.x * 32, r0 = blockIdx.y * 32;
    const int tx = threadIdx.x & 31, ty = threadIdx.x >> 5;   // ty 0..7
    #pragma unroll
    for (int i = 0; i < 4; ++i)
        tile[ty + 8 * i][tx] = W[(long)(r0 + ty + 8 * i) * CC + c0 + tx];
    __syncthreads();
    #pragma unroll
    for (int i = 0; i < 4; ++i)
        WT[(long)(c0 + ty + 8 * i) * CC + r0 + tx] = f2bf(tile[tx][ty + 8 * i]);
}

// bf16 vvb [B][NS2][CC] -> bf16 vvT [B][CC][NS2]
__global__ void trans_vv(const unsigned short* __restrict__ vvb, unsigned short* __restrict__ vvT)
{
    __shared__ unsigned short tile[32][34];
    const int b = blockIdx.z;
    const int n0 = blockIdx.x * 32, c0 = blockIdx.y * 32;
    const int tx = threadIdx.x & 31, ty = threadIdx.x >> 5;
    const long ib = (long)b * NS2 * CC;
    #pragma unroll
    for (int i = 0; i < 4; ++i)
        tile[ty + 8 * i][tx] = vvb[ib + (long)(n0 + ty + 8 * i) * CC + c0 + tx];
    __syncthreads();
    #pragma unroll
    for (int i = 0; i < 4; ++i)
        vvT[ib + (long)(c0 + ty + 8 * i) * NS2 + n0 + tx] = tile[tx][ty + 8 * i];
}

// =================== softmax over 576 cols ===================
// P fp32 [B][NTP][NS2]; grid (B*NTP, 2); in-place normalize + write bf16 Pb.
// Pad rows (t>=NT): zero Pb only.
__global__ void softmax576(float* __restrict__ P, unsigned short* __restrict__ Pb)
{
    const int rowp = blockIdx.x;
    const int t = rowp % NTP;
    const long base = (long)rowp * NS2 + blockIdx.y * NS;
    const int tid = threadIdx.x;
    if (t >= NT) {
        Pb[base + tid] = 0; Pb[base + tid + 256] = 0;
        if (tid < NS - 512) Pb[base + tid + 512] = 0;
        return;
    }
    float* p = P + base;
    float v0 = p[tid];
    float v1 = p[tid + 256];
    float v2 = (tid < NS - 512) ? p[tid + 512] : -1e30f;
    float m = block_max256(fmaxf(fmaxf(v0, v1), v2));
    float e0 = __expf(v0 - m);
    float e1 = __expf(v1 - m);
    float e2 = (tid < NS - 512) ? __expf(v2 - m) : 0.f;
    float s = block_sum256(e0 + e1 + e2);
    float inv = 1.f / s;
    e0 *= inv; e1 *= inv; e2 *= inv;
    p[tid] = e0;             Pb[base + tid] = f2bf(e0);
    p[tid + 256] = e1;       Pb[base + tid + 256] = f2bf(e1);
    if (tid < NS - 512) { p[tid + 512] = e2; Pb[base + tid + 512] = f2bf(e2); }
}

// =================== sign counts over D = aw - awi ===================
// ratios[2g] = rgb+eq (coef of v), ratios[2g+1] = tir+eq (coef of vi)
__global__ void count_ratio(const float* __restrict__ P, float* __restrict__ ratios)
{
    int g = blockIdx.x * 256 + threadIdx.x;     // 0 .. BB*NS-1
    int b = g / NS, n = g - b * NS;
    const float* pa = P + (long)b * NTP * NS2 + n;
    int ones = 0, eq = 0;
    #pragma unroll 4
    for (int t = 0; t < NT; ++t) {
        const float* row = pa + (long)t * NS2;
        float d = row[0] - row[NS];
        ones += (d > 0.f);
        eq   += (d == 0.f);
    }
    float rgb = (float)ones * (1.f / NT);
    float e   = (float)eq   * (1.f / NT);
    ratios[2 * g]     = rgb + e;
    ratios[2 * g + 1] = (1.f - rgb - e) + e;
}

// =================== x_s = v*coef_v + vi*coef_vi (bf16 v) ===================
__global__ void xs_kernel(const unsigned short* __restrict__ vvb,
                          const float* __restrict__ ratios, float* __restrict__ out)
{
    long j = ((long)blockIdx.x * 256 + threadIdx.x) * 2;   // over BB*NS*CC
    int c = (int)(j % CC);
    long row = j / CC;            // b*NS + n
    long b = row / NS, n = row - b * NS;
    long vo  = (b * NS2 + n) * CC + c;
    unsigned pv  = *(const unsigned*)(vvb + vo);
    unsigned pvi = *(const unsigned*)(vvb + vo + (long)NS * CC);
    float c1 = ratios[2 * row], c2 = ratios[2 * row + 1];
    float2 o;
    o.x = bf2f((unsigned short)(pv & 0xFFFF))  * c1 + bf2f((unsigned short)(pvi & 0xFFFF))  * c2;
    o.y = bf2f((unsigned short)(pv >> 16))     * c1 + bf2f((unsigned short)(pvi >> 16))     * c2;
    *(float2*)(out + j) = o;
}

// =================== T_new = LayerNorm(T + S2) ===================
__global__ void add_ln(const float* __restrict__ T, const float* __restrict__ S2,
                       const float* __restrict__ gamma, const float* __restrict__ beta,
                       float* __restrict__ out)
{
    const int r = blockIdx.x;                 // b*NT + t
    const int b = r / NT, t = r - b * NT;
    const int tid = threadIdx.x;
    const float* tp = T + (long)r * CC;
    const float* sp = S2 + ((long)b * NTP + t) * CC;
    float h[3];
    float sum = 0.f;
    #pragma unroll
    for (int i = 0; i < 3; ++i) {
        h[i] = tp[tid + 256 * i] + sp[tid + 256 * i];
        sum += h[i];
    }
    sum = block_sum256(sum);
    float mu = sum * (1.f / CC);
    float varp = 0.f;
    #pragma unroll
    for (int i = 0; i < 3; ++i) { float d = h[i] - mu; varp += d * d; }
    varp = block_sum256(varp);
    float inv = rsqrtf(varp * (1.f / CC) + LN_EPS);
    #pragma unroll
    for (int i = 0; i < 3; ++i) {
        int c = tid + 256 * i;
        out[(long)r * CC + c] = (h[i] - mu) * inv * gamma[c] + beta[c];
    }
}

// =================== launch ===================
extern "C" void kernel_launch(void* const* d_in, const int* in_sizes, int n_in,
                              void* d_out, int out_size, void* d_ws, size_t ws_size,
                              hipStream_t stream) {
    const float* T     = (const float*)d_in[0];
    const float* x     = (const float*)d_in[1];
    const float* xi    = (const float*)d_in[2];
    const float* Wq    = (const float*)d_in[3];
    const float* Wk    = (const float*)d_in[4];
    const float* Wv    = (const float*)d_in[5];
    const float* Wout  = (const float*)d_in[6];
    const float* gamma = (const float*)d_in[7];
    const float* beta  = (const float*)d_in[8];
    float* out = (float*)d_out;

    // ---- workspace layout (bytes) ----
    const long B_TB  = (long)BB * NTP * CC * 2;        // 18,874,368  (Tb, later Sb)
    const long B_QB  = (long)BB * NTP * CC * 2;        // qb
    const long B_KK  = (long)BB * NS2 * CC * 2;        // 56,623,104  (k|ki)
    const long B_WT  = (long)CC * CC * 2;              // 1,179,648 each
    const long B_VV  = (long)BB * NS2 * CC * 2;        // vvb (later S2 fp32 fits: 37.7MB)
    const long B_VVT = (long)BB * CC * NS2 * 2;        // vvT
    const long B_XS  = (long)BB * NSP * CC * 2;        // xsb
    const long B_P   = 2 * B_XS;                       // xsb+xisb region; P fp32 (56.6MB) overlays
    const long B_PB  = (long)BB * NTP * NS2 * 2;       // 28,311,552
    const long B_RT  = 2L * BB * NS * 4;

    char* cur = (char*)d_ws;
    unsigned short* Tb   = (unsigned short*)cur; cur += B_TB;
    unsigned short* qb   = (unsigned short*)cur; cur += B_QB;
    unsigned short* kkb  = (unsigned short*)cur; cur += B_KK;
    unsigned short* WqT  = (unsigned short*)cur; cur += B_WT;
    unsigned short* WkT  = (unsigned short*)cur; cur += B_WT;
    unsigned short* WvT  = (unsigned short*)cur; cur += B_WT;
    unsigned short* WoT  = (unsigned short*)cur; cur += B_WT;
    unsigned short* vvb  = (unsigned short*)cur; cur += B_VV;
    unsigned short* vvT  = (unsigned short*)cur; cur += B_VVT;
    unsigned short* xsb  = (unsigned short*)cur;
    unsigned short* xisb = xsb + (long)BB * NSP * CC;  cur += B_P;
    unsigned short* Pb   = (unsigned short*)cur; cur += B_PB;
    float* ratios        = (float*)cur; cur += B_RT;
    if ((size_t)(cur - (char*)d_ws) > ws_size) return;   // 303.7 MB needed

    unsigned short* Sb = Tb;            // Tb dead after q GEMM
    float* P  = (float*)xsb;            // xsb/xisb dead after projections
    float* S2 = (float*)vvb;            // vvb dead after xs + transpose

    const float scale = 1.0f / sqrtf((float)CC);
    dim3 blk(256);

    // 1. converts
    conv_pad<<<(BB * NTP * CC) / 1024, blk, 0, stream>>>(T,  Tb,   NT, NTP, NT, 0);
    conv_pad<<<(BB * NSP * CC) / 1024, blk, 0, stream>>>(x,  xsb,  NS, NSP, LX, TMPL);
    conv_pad<<<(BB * NSP * CC) / 1024, blk, 0, stream>>>(xi, xisb, NS, NSP, LX, TMPL);
    dim3 wtg(CC / 32, CC / 32);
    conv_wt<<<wtg, blk, 0, stream>>>(Wq,   WqT);
    conv_wt<<<wtg, blk, 0, stream>>>(Wk,   WkT);
    conv_wt<<<wtg, blk, 0, stream>>>(Wv,   WvT);
    conv_wt<<<wtg, blk, 0, stream>>>(Wout, WoT);

    // 2. projections (bf16 out)
    gemm_bt<false><<<dim3(CC / 128, NTP / 128, BB), blk, 0, stream>>>(
        (const short*)Tb, (const short*)WqT, qb, NT, CC, CC,
        (long)NTP * CC, 0, (long)NTP * CC, 1.f);
    gemm_bt<false><<<dim3(CC / 128, NSP / 128, BB), blk, 0, stream>>>(
        (const short*)xsb, (const short*)WkT, kkb, NS, CC, CC,
        (long)NSP * CC, 0, (long)NS2 * CC, 1.f);
    gemm_bt<false><<<dim3(CC / 128, NSP / 128, BB), blk, 0, stream>>>(
        (const short*)xisb, (const short*)WkT, kkb + (long)NS * CC, NS, CC, CC,
        (long)NSP * CC, 0, (long)NS2 * CC, 1.f);
    gemm_bt<false><<<dim3(CC / 128, NSP / 128, BB), blk, 0, stream>>>(
        (const short*)xsb, (const short*)WvT, vvb, NS, CC, CC,
        (long)NSP * CC, 0, (long)NS2 * CC, 1.f);
    gemm_bt<false><<<dim3(CC / 128, NSP / 128, BB), blk, 0, stream>>>(
        (const short*)xisb, (const short*)WvT, vvb + (long)NS * CC, NS, CC, CC,
        (long)NSP * CC, 0, (long)NS2 * CC, 1.f);

    // 3. transpose v|vi for PV GEMM B operand
    trans_vv<<<dim3(NS2 / 32, CC / 32, BB), blk, 0, stream>>>(vvb, vvT);

    // 4. logits (fp32 out): P = scale * q @ [k|ki]^T   N=1152
    gemm_bt<true><<<dim3(NS2 / 128, NTP / 128, BB), blk, 0, stream>>>(
        (const short*)qb, (const short*)kkb, P, NT, NS2, CC,
        (long)NTP * CC, (long)NS2 * CC, (long)NTP * NS2, scale);

    // 5. softmax (fp32 in place + bf16 Pb; zeros Pb pad rows)
    softmax576<<<dim3(BB * NTP, 2), blk, 0, stream>>>(P, Pb);

    // 6. ratios from sign counts of D = aw - awi
    count_ratio<<<(BB * NS) / 256, blk, 0, stream>>>(P, ratios);

    // 7. x_s -> d_out[0 : BB*NS*CC]
    xs_kernel<<<(BB * NS * CC) / 512, blk, 0, stream>>>(vvb, ratios, out);

    // 8. S = [aw|awi] @ [v;vi]  (bf16 out, K=1152)
    gemm_bt<false><<<dim3(CC / 128, NTP / 128, BB), blk, 0, stream>>>(
        (const short*)Pb, (const short*)vvT, Sb, NT, CC, NS2,
        (long)NTP * NS2, (long)CC * NS2, (long)NTP * CC, 1.f);

    // 9. S2 = S @ Wout  (fp32 out)
    gemm_bt<true><<<dim3(CC / 128, NTP / 128, BB), blk, 0, stream>>>(
        (const short*)Sb, (const short*)WoT, S2, NT, CC, CC,
        (long)NTP * CC, 0, (long)NTP * CC, 1.f);

    // 10. T_new = LN(T + S2) -> d_out tail
    add_ln<<<BB * NT, blk, 0, stream>>>(T, S2, gamma, beta, out + (long)BB * NS * CC);
}

// Round 3
// 665.401 us; speedup vs baseline: 4.5041x; 1.0895x over previous
//
#include <hip/hip_runtime.h>

// Problem constants
#define BB   32
#define NT   320      // T rows per batch (= 5*64)
#define LX   704
#define TMPL 128
#define NS   576      // LX - TMPL (= 9*64)
#define CC   768
#define NS2  1152     // 2*NS
#define LN_EPS 1e-5f

typedef __attribute__((ext_vector_type(8))) short short8;   // 8 bf16 (4 VGPRs)
typedef __attribute__((ext_vector_type(4))) float f32x4;
typedef unsigned long long u64;

typedef __attribute__((address_space(3))) void as3_void;
typedef __attribute__((address_space(1))) void as1_void;
#define GLDS16(g, l) __builtin_amdgcn_global_load_lds((const as1_void*)(g), (as3_void*)(l), 16, 0, 0)

__device__ __forceinline__ unsigned short f2bf(float f) {
    union { float f; unsigned u; } v; v.f = f;
    unsigned r = v.u + 0x7FFFu + ((v.u >> 16) & 1u);   // RNE
    return (unsigned short)(r >> 16);
}
__device__ __forceinline__ float bf2f(unsigned short h) {
    union { unsigned u; float f; } v; v.u = ((unsigned)h) << 16;
    return v.f;
}

// ---------------- block reductions (blockDim == 256) ----------------
__device__ __forceinline__ float block_sum256(float v) {
    __shared__ float sm[4];
    #pragma unroll
    for (int o = 32; o > 0; o >>= 1) v += __shfl_down(v, o, 64);
    __syncthreads();
    if ((threadIdx.x & 63) == 0) sm[threadIdx.x >> 6] = v;
    __syncthreads();
    return sm[0] + sm[1] + sm[2] + sm[3];
}
__device__ __forceinline__ float block_max256(float v) {
    __shared__ float sm[4];
    #pragma unroll
    for (int o = 32; o > 0; o >>= 1) v = fmaxf(v, __shfl_down(v, o, 64));
    __syncthreads();
    if ((threadIdx.x & 63) == 0) sm[threadIdx.x >> 6] = v;
    __syncthreads();
    return fmaxf(fmaxf(sm[0], sm[1]), fmaxf(sm[2], sm[3]));
}

// =================== bf16 MFMA GEMM core: BM=64, BN=128, BK=32 ===================
// C(M x N) = alpha * A(M x K, row-major bf16) @ Bt(N x K, row-major bf16)^T
// 256 threads = 4 waves in 2x2; wave tile 32x64 (2x4 MFMA 16x16x32).
// M multiple of 64 (exact; no store guards), N % 128 == 0, K % 32 == 0.
// LDS chunk-swizzle: global 16B k-chunk g lives at position p = g ^ ((row>>1)&3)
// -> ds_read_b128 starting banks spread over 8 values (2-way = free).
template<bool F32OUT>
__device__ __forceinline__ void gemm64_core(const short* __restrict__ Ab,
                                            const short* __restrict__ Bb,
                                            void* __restrict__ Cb,
                                            int N, int K, float alpha)
{
    __shared__ short As[64 * 32];    // 4 KB
    __shared__ short Bs[128 * 32];   // 8 KB
    const int m0 = blockIdx.y * 64;
    const int n0 = blockIdx.x * 128;
    const int tid  = threadIdx.x;
    const int lane = tid & 63;
    const int w    = tid >> 6;
    const int wr   = (w >> 1) * 32;   // wave row in tile
    const int wc   = (w & 1) * 64;    // wave col in tile

    // staging: thread t covers LDS offset t*16B (lane-contiguous per wave);
    // global k-chunk fetched is swizzled by row.
    const int srow = tid >> 2;
    const int g    = ((tid & 3) ^ ((srow >> 1) & 3)) * 8;
    const short* gA  = Ab + (long)(m0 + srow) * K + g;
    const short* gB0 = Bb + (long)(n0 + srow) * K + g;
    const short* gB1 = gB0 + (long)64 * K;
    short* lA  = As + tid * 8;
    short* lB0 = Bs + tid * 8;
    short* lB1 = Bs + 2048 + tid * 8;

    const int fl = lane & 15;         // m/n within 16-tile
    const int ch = lane >> 4;         // k-chunk index 0..3

    f32x4 acc[2][4] = {};

    for (int k0 = 0; k0 < K; k0 += 32) {
        GLDS16(gA  + k0, lA);
        GLDS16(gB0 + k0, lB0);
        GLDS16(gB1 + k0, lB1);
        __syncthreads();

        short8 af[2], bfv[4];
        #pragma unroll
        for (int mt = 0; mt < 2; ++mt) {
            int row = wr + mt * 16 + fl;
            af[mt] = *(const short8*)(As + row * 32 + ((ch ^ ((row >> 1) & 3)) * 8));
        }
        #pragma unroll
        for (int nt = 0; nt < 4; ++nt) {
            int row = wc + nt * 16 + fl;
            bfv[nt] = *(const short8*)(Bs + row * 32 + ((ch ^ ((row >> 1) & 3)) * 8));
        }
        #pragma unroll
        for (int mt = 0; mt < 2; ++mt)
            #pragma unroll
            for (int nt = 0; nt < 4; ++nt)
                acc[mt][nt] = __builtin_amdgcn_mfma_f32_16x16x32_bf16(
                    af[mt], bfv[nt], acc[mt][nt], 0, 0, 0);
        __syncthreads();
    }

    // epilogue: C/D layout col=lane&15, row=(lane>>4)*4+reg
    float* Cf = (float*)Cb;
    unsigned short* Ch = (unsigned short*)Cb;
    const int rq = (lane >> 4) * 4;
    #pragma unroll
    for (int mt = 0; mt < 2; ++mt) {
        #pragma unroll
        for (int r = 0; r < 4; ++r) {
            long ro = (long)(m0 + wr + mt * 16 + rq + r) * N + n0 + wc + fl;
            #pragma unroll
            for (int nt = 0; nt < 4; ++nt) {
                float val = acc[mt][nt][r] * alpha;
                if (F32OUT) Cf[ro + nt * 16] = val;
                else        Ch[ro + nt * 16] = f2bf(val);
            }
        }
    }
}

template<bool F32OUT>
__global__ __launch_bounds__(256) void gemm64(
    const short* __restrict__ A, const short* __restrict__ Bt, void* __restrict__ C,
    int N, int K, long sA, long sB, long sC, float alpha)
{
    const int b = blockIdx.z;
    void* Cb = F32OUT ? (void*)((float*)C + (long)b * sC)
                      : (void*)((unsigned short*)C + (long)b * sC);
    gemm64_core<F32OUT>(A + (long)b * sA, Bt + (long)b * sB, Cb, N, K, alpha);
}

// merged 4-way projection: z = b*4 + which; which: 0=k,1=ki,2=v,3=vi
__global__ __launch_bounds__(256) void proj4(
    const short* __restrict__ xsb, const short* __restrict__ xisb,
    const short* __restrict__ WkT, const short* __restrict__ WvT,
    unsigned short* __restrict__ kkb, unsigned short* __restrict__ vvb)
{
    const int which = blockIdx.z & 3;
    const int b     = blockIdx.z >> 2;
    const short* A  = ((which & 1) ? xisb : xsb) + (long)b * NS * CC;
    const short* Bt = (which & 2) ? WvT : WkT;
    unsigned short* C = ((which & 2) ? vvb : kkb)
                        + (long)b * NS2 * CC + (long)(which & 1) * NS * CC;
    gemm64_core<false>(A, Bt, C, CC, CC, 1.f);
}

// =================== input converts (fp32 -> bf16), merged ===================
// blockIdx.y: 0 = T (320 rows), 1 = x (rows TMPL..), 2 = xi
__global__ void conv_in(const float* __restrict__ T, const float* __restrict__ x,
                        const float* __restrict__ xi,
                        unsigned short* __restrict__ Tb, unsigned short* __restrict__ xsb,
                        unsigned short* __restrict__ xisb)
{
    const int which = blockIdx.y;
    long i4 = ((long)blockIdx.x * 256 + threadIdx.x) * 4;
    const float* src; unsigned short* dst; long total; int rows, off, rpb;
    if (which == 0) { src = T;  dst = Tb;   total = (long)BB * NT * CC; rows = NT; off = 0;    rpb = NT; }
    else if (which == 1) { src = x;  dst = xsb;  total = (long)BB * NS * CC; rows = LX; off = TMPL; rpb = NS; }
    else            { src = xi; dst = xisb; total = (long)BB * NS * CC; rows = LX; off = TMPL; rpb = NS; }
    if (i4 >= total) return;
    int c   = (int)(i4 % CC);
    long rw = i4 / CC;
    int t   = (int)(rw % rpb);
    int b   = (int)(rw / rpb);
    const float4 f = *(const float4*)(src + ((long)b * rows + off + t) * CC + c);
    ushort4 o;
    o.x = f2bf(f.x); o.y = f2bf(f.y); o.z = f2bf(f.z); o.w = f2bf(f.w);
    *(ushort4*)(dst + i4) = o;
}

// fp32 W [CC][CC] -> bf16 W^T [CC][CC], 4 weights via blockIdx.z
__global__ void conv_wt4(const float* __restrict__ Wq, const float* __restrict__ Wk,
                         const float* __restrict__ Wv, const float* __restrict__ Wo,
                         unsigned short* __restrict__ WqT, unsigned short* __restrict__ WkT,
                         unsigned short* __restrict__ WvT, unsigned short* __restrict__ WoT)
{
    const float* W; unsigned short* WT;
    switch (blockIdx.z) {
        case 0: W = Wq; WT = WqT; break;
        case 1: W = Wk; WT = WkT; break;
        case 2: W = Wv; WT = WvT; break;
        default: W = Wo; WT = WoT; break;
    }
    __shared__ float tile[32][33];
    const int c0 = blockIdx.x * 32, r0 = blockIdx.y * 32;
    const int tx = threadIdx.x & 31, ty = threadIdx.x >> 5;
    #pragma unroll
    for (int i = 0; i < 4; ++i)
        tile[ty + 8 * i][tx] = W[(long)(r0 + ty + 8 * i) * CC + c0 + tx];
    __syncthreads();
    #pragma unroll
    for (int i = 0; i < 4; ++i)
        WT[(long)(c0 + ty + 8 * i) * CC + r0 + tx] = f2bf(tile[tx][ty + 8 * i]);
}

// bf16 vvb [B][NS2][CC] -> bf16 vvT [B][CC][NS2]
__global__ void trans_vv(const unsigned short* __restrict__ vvb, unsigned short* __restrict__ vvT)
{
    __shared__ unsigned short tile[32][34];
    const int b = blockIdx.z;
    const int n0 = blockIdx.x * 32, c0 = blockIdx.y * 32;
    const int tx = threadIdx.x & 31, ty = threadIdx.x >> 5;
    const long ib = (long)b * NS2 * CC;
    #pragma unroll
    for (int i = 0; i < 4; ++i)
        tile[ty + 8 * i][tx] = vvb[ib + (long)(n0 + ty + 8 * i) * CC + c0 + tx];
    __syncthreads();
    #pragma unroll
    for (int i = 0; i < 4; ++i)
        vvT[ib + (long)(c0 + ty + 8 * i) * NS2 + n0 + tx] = tile[tx][ty + 8 * i];
}

// =================== fused dual softmax + bf16 write + sign-pack ===================
// one block per (b,t) row of P fp32 [B*NT][NS2]; both 576-halves.
// posm/eqm: [B*NT][9] u64 bitmasks over n (bit n&63 of word n>>6).
__global__ void softmax_pack(const float* __restrict__ P, unsigned short* __restrict__ Pb,
                             u64* __restrict__ posm, u64* __restrict__ eqm)
{
    const long r = blockIdx.x;          // b*NT + t
    const float* p = P + r * NS2;
    const int tid = threadIdx.x;

    float a0 = p[tid], a1 = p[tid + 256], a2 = (tid < 64) ? p[tid + 512] : -1e30f;
    float m1 = block_max256(fmaxf(fmaxf(a0, a1), a2));
    float e0 = __expf(a0 - m1), e1 = __expf(a1 - m1), e2 = (tid < 64) ? __expf(a2 - m1) : 0.f;
    float s1 = block_sum256(e0 + e1 + e2);
    float i1 = 1.f / s1;
    e0 *= i1; e1 *= i1; e2 *= i1;

    const float* q = p + NS;
    float b0 = q[tid], b1 = q[tid + 256], b2 = (tid < 64) ? q[tid + 512] : -1e30f;
    float m2 = block_max256(fmaxf(fmaxf(b0, b1), b2));
    float f0 = __expf(b0 - m2), f1 = __expf(b1 - m2), f2v = (tid < 64) ? __expf(b2 - m2) : 0.f;
    float s2 = block_sum256(f0 + f1 + f2v);
    float i2 = 1.f / s2;
    f0 *= i2; f1 *= i2; f2v *= i2;

    unsigned short* ob = Pb + r * NS2;
    ob[tid] = f2bf(e0); ob[tid + 256] = f2bf(e1);
    if (tid < 64) ob[tid + 512] = f2bf(e2);
    ob[NS + tid] = f2bf(f0); ob[NS + tid + 256] = f2bf(f1);
    if (tid < 64) ob[NS + tid + 512] = f2bf(f2v);

    u64* pm = posm + r * 9;
    u64* em = eqm  + r * 9;
    const int wv = tid >> 6;
    float d0 = e0 - f0, d1 = e1 - f1, d2 = e2 - f2v;
    u64 P0 = __ballot(d0 > 0.f), E0 = __ballot(d0 == 0.f);
    if ((tid & 63) == 0) { pm[wv] = P0; em[wv] = E0; }
    u64 P1 = __ballot(d1 > 0.f), E1 = __ballot(d1 == 0.f);
    if ((tid & 63) == 0) { pm[4 + wv] = P1; em[4 + wv] = E1; }
    u64 P2 = __ballot(tid < 64 && d2 > 0.f), E2 = __ballot(tid < 64 && d2 == 0.f);
    if (tid == 0) { pm[8] = P2; em[8] = E2; }
}

// =================== fused count + x_s ===================
// one block per (b,n): popcount sign bits over t, then scale v/vi row -> out.
__global__ void xs_fused(const u64* __restrict__ posm, const u64* __restrict__ eqm,
                         const unsigned short* __restrict__ vvb, float* __restrict__ out)
{
    const int gid = blockIdx.x;          // b*NS + n
    const int b = gid / NS, n = gid - b * NS;
    const int tid = threadIdx.x;
    const int wsel = n >> 6, bit = n & 63;
    float ones = 0.f, eqc = 0.f;
    for (int t = tid; t < NT; t += 256) {
        long o = ((long)(b * NT + t)) * 9 + wsel;
        ones += (float)((posm[o] >> bit) & 1);
        eqc  += (float)((eqm[o]  >> bit) & 1);
    }
    ones = block_sum256(ones);
    eqc  = block_sum256(eqc);
    float rgb = ones * (1.f / NT), e = eqc * (1.f / NT);
    float c1 = rgb + e;
    float c2 = (1.f - rgb - e) + e;
    const unsigned* pv  = (const unsigned*)(vvb + ((long)b * NS2 + n) * CC);
    const unsigned* pvi = (const unsigned*)(vvb + ((long)b * NS2 + n + NS) * CC);
    float* po = out + ((long)b * NS + n) * CC;
    for (int idx = tid; idx < CC / 2; idx += 256) {
        unsigned a = pv[idx], bb = pvi[idx];
        float2 o2;
        o2.x = bf2f((unsigned short)(a & 0xFFFF)) * c1 + bf2f((unsigned short)(bb & 0xFFFF)) * c2;
        o2.y = bf2f((unsigned short)(a >> 16))    * c1 + bf2f((unsigned short)(bb >> 16))    * c2;
        *(float2*)(po + 2 * idx) = o2;
    }
}

// =================== T_new = LayerNorm(T + S2) ===================
__global__ void add_ln(const float* __restrict__ T, const float* __restrict__ S2,
                       const float* __restrict__ gamma, const float* __restrict__ beta,
                       float* __restrict__ out)
{
    const long r = blockIdx.x;            // b*NT + t
    const int tid = threadIdx.x;
    const float* tp = T  + r * CC;
    const float* sp = S2 + r * CC;
    float h[3];
    float sum = 0.f;
    #pragma unroll
    for (int i = 0; i < 3; ++i) {
        h[i] = tp[tid + 256 * i] + sp[tid + 256 * i];
        sum += h[i];
    }
    sum = block_sum256(sum);
    float mu = sum * (1.f / CC);
    float varp = 0.f;
    #pragma unroll
    for (int i = 0; i < 3; ++i) { float d = h[i] - mu; varp += d * d; }
    varp = block_sum256(varp);
    float inv = rsqrtf(varp * (1.f / CC) + LN_EPS);
    #pragma unroll
    for (int i = 0; i < 3; ++i) {
        int c = tid + 256 * i;
        out[r * CC + c] = (h[i] - mu) * inv * gamma[c] + beta[c];
    }
}

// =================== launch ===================
extern "C" void kernel_launch(void* const* d_in, const int* in_sizes, int n_in,
                              void* d_out, int out_size, void* d_ws, size_t ws_size,
                              hipStream_t stream) {
    const float* T     = (const float*)d_in[0];
    const float* x     = (const float*)d_in[1];
    const float* xi    = (const float*)d_in[2];
    const float* Wq    = (const float*)d_in[3];
    const float* Wk    = (const float*)d_in[4];
    const float* Wv    = (const float*)d_in[5];
    const float* Wout  = (const float*)d_in[6];
    const float* gamma = (const float*)d_in[7];
    const float* beta  = (const float*)d_in[8];
    float* out = (float*)d_out;

    // ---- workspace layout (bytes), ~288 MB ----
    const long B_T  = (long)BB * NT * CC * 2;         // 15.7 MB (Tb; later Sb)
    const long B_KK = (long)BB * NS2 * CC * 2;        // 56.6 MB
    const long B_WT = (long)CC * CC * 2;              // 1.18 MB each
    const long B_XS = (long)BB * NS * CC * 2;         // 28.3 MB each; pair overlaid by P fp32 (47.2 MB)
    const long B_PB = (long)BB * NT * NS2 * 2;        // 23.6 MB
    const long B_MK = (long)BB * NT * 9 * 8;          // 0.74 MB each

    char* cur = (char*)d_ws;
    unsigned short* Tb   = (unsigned short*)cur; cur += B_T;
    unsigned short* qb   = (unsigned short*)cur; cur += B_T;
    unsigned short* kkb  = (unsigned short*)cur; cur += B_KK;
    unsigned short* WqT  = (unsigned short*)cur; cur += B_WT;
    unsigned short* WkT  = (unsigned short*)cur; cur += B_WT;
    unsigned short* WvT  = (unsigned short*)cur; cur += B_WT;
    unsigned short* WoT  = (unsigned short*)cur; cur += B_WT;
    unsigned short* vvb  = (unsigned short*)cur; cur += B_KK;
    unsigned short* vvT  = (unsigned short*)cur; cur += B_KK;
    unsigned short* xsb  = (unsigned short*)cur;
    unsigned short* xisb = xsb + (long)BB * NS * CC;  cur += 2 * B_XS;
    unsigned short* Pb   = (unsigned short*)cur; cur += B_PB;
    u64* posm            = (u64*)cur; cur += B_MK;
    u64* eqm             = (u64*)cur; cur += B_MK;
    if ((size_t)(cur - (char*)d_ws) > ws_size) return;

    float* P  = (float*)xsb;    // xsb/xisb dead after projections; 47.2 <= 56.6 MB
    unsigned short* Sb = Tb;    // Tb dead after q GEMM
    float* S2 = (float*)vvb;    // vvb dead after xs_fused; 31.5 <= 56.6 MB

    const float scale = 1.0f / sqrtf((float)CC);
    dim3 blk(256);

    // 1. converts (2 dispatches)
    conv_in<<<dim3((BB * NS * CC) / 1024, 3), blk, 0, stream>>>(T, x, xi, Tb, xsb, xisb);
    conv_wt4<<<dim3(CC / 32, CC / 32, 4), blk, 0, stream>>>(Wq, Wk, Wv, Wout, WqT, WkT, WvT, WoT);

    // 2. merged KV projections: 6912 blocks (~27/CU)
    proj4<<<dim3(CC / 128, NS / 64, BB * 4), blk, 0, stream>>>(
        (const short*)xsb, (const short*)xisb, (const short*)WkT, (const short*)WvT, kkb, vvb);

    // 3. q = T @ Wq
    gemm64<false><<<dim3(CC / 128, NT / 64, BB), blk, 0, stream>>>(
        (const short*)Tb, (const short*)WqT, qb, CC, CC,
        (long)NT * CC, 0, (long)NT * CC, 1.f);

    // 4. transpose v|vi for PV B operand
    trans_vv<<<dim3(NS2 / 32, CC / 32, BB), blk, 0, stream>>>(vvb, vvT);

    // 5. logits (fp32): P = scale * q @ [k|ki]^T
    gemm64<true><<<dim3(NS2 / 128, NT / 64, BB), blk, 0, stream>>>(
        (const short*)qb, (const short*)kkb, P, NS2, CC,
        (long)NT * CC, (long)NS2 * CC, (long)NT * NS2, scale);

    // 6. dual softmax + bf16 P + sign masks
    softmax_pack<<<BB * NT, blk, 0, stream>>>(P, Pb, posm, eqm);

    // 7. fused count + x_s -> d_out[0 : B*NS*CC]
    xs_fused<<<BB * NS, blk, 0, stream>>>(posm, eqm, vvb, out);

    // 8. S = [aw|awi] @ [v;vi]   (bf16, K=1152)
    gemm64<false><<<dim3(CC / 128, NT / 64, BB), blk, 0, stream>>>(
        (const short*)Pb, (const short*)vvT, Sb, CC, NS2,
        (long)NT * NS2, (long)CC * NS2, (long)NT * CC, 1.f);

    // 9. S2 = S @ Wout  (fp32)
    gemm64<true><<<dim3(CC / 128, NT / 64, BB), blk, 0, stream>>>(
        (const short*)Sb, (const short*)WoT, S2, CC, CC,
        (long)NT * CC, 0, (long)NT * CC, 1.f);

    // 10. T_new = LN(T + S2) -> d_out tail
    add_ln<<<BB * NT, blk, 0, stream>>>(T, S2, gamma, beta, out + (long)BB * NS * CC);
}